// Round 7
// baseline (184.422 us; speedup 1.0000x reference)
//
#include <hip/hip_runtime.h>
#include <hip/hip_bf16.h>
#include <math.h>

#define B_ 2
#define T_ 2048
#define E_ 1024
#define H_ 16
#define D_ 64
#define NT_ 32          // T/64 tiles
#define QSCALE 0.180336880f   // 0.125 * log2(e): folded into q so exp(S/8) = exp2(S')

typedef __attribute__((ext_vector_type(8))) short bf16x8;   // MFMA A/B frag (4 VGPRs)
typedef __attribute__((ext_vector_type(4))) float f32x4;    // MFMA C/D frag

#if __has_builtin(__builtin_amdgcn_exp2f)
#define EXP2(x) __builtin_amdgcn_exp2f(x)
#else
#define EXP2(x) exp2f(x)
#endif

__device__ __forceinline__ unsigned short f2bf(float x) {   // RNE fp32->bf16
  union { float f; unsigned u; } v; v.f = x;
  unsigned r = v.u + 0x7FFFu + ((v.u >> 16) & 1u);
  return (unsigned short)(r >> 16);
}
__device__ __forceinline__ unsigned pk2bf(float a, float b) {  // low=a, high=b (HW cvt_pk)
  __hip_bfloat162 h = __float22bfloat162_rn(make_float2(a, b));
  union { __hip_bfloat162 h; unsigned u; } c; c.h = h; return c.u;
}

// Async global->LDS: one wave-instr stages 8 rows x 64 bf16 (8 blocks of 16B),
// XOR-swizzled: LDS slot (row, bs) holds global block bs ^ (row&7).
__device__ __forceinline__ void dma8(const unsigned short* g, int gstride,
                                     unsigned short* l, int lane)
{
  const int r = lane >> 3, bg = (lane & 7) ^ (r & 7);
  __builtin_amdgcn_global_load_lds(
      (const __attribute__((address_space(1))) void*)(g + (size_t)r * gstride + bg * 8),
      (__attribute__((address_space(3))) void*)l, 16, 0, 0);
}
__device__ __forceinline__ bf16x8 frag(const unsigned short* tile, int row, int g) {
  return *(const bf16x8*)(tile + row * 64 + (((g ^ row) & 7) << 3));
}

// ---------------------------------------------------------------------------
// input pre-pack: (B,T,E) fp32 -> bf16. grid 2048 x 256.
// ---------------------------------------------------------------------------
__global__ __launch_bounds__(256) void inpack_kernel(const float* __restrict__ in,
                                                     unsigned short* __restrict__ o) {
  const size_t i = ((size_t)blockIdx.x * 256 + threadIdx.x) * 8;
  float4 f0 = *(const float4*)(in + i);
  float4 f1 = *(const float4*)(in + i + 4);
  unsigned u[4] = { pk2bf(f0.x, f0.y), pk2bf(f0.z, f0.w),
                    pk2bf(f1.x, f1.y), pk2bf(f1.z, f1.w) };
  *(bf16x8*)(o + i) = *(const bf16x8*)u;
}

// ---------------------------------------------------------------------------
// weight pack: (H,E,D) fp32 -> (H,D,E) bf16. grid (E/64, H, 3) x 256.
// ---------------------------------------------------------------------------
__global__ __launch_bounds__(256) void wpack_kernel(
    const float* __restrict__ qw, const float* __restrict__ kw, const float* __restrict__ vw,
    unsigned short* __restrict__ qwt, unsigned short* __restrict__ kwt,
    unsigned short* __restrict__ vwt)
{
  __shared__ float s[64][65];
  const int tid = threadIdx.x;
  const int e0 = blockIdx.x * 64, h = blockIdx.y, z = blockIdx.z;
  const float* w = (z == 0) ? qw : (z == 1) ? kw : vw;
  unsigned short* o = (z == 0) ? qwt : (z == 1) ? kwt : vwt;
  {
    const int r = tid >> 2;
    #pragma unroll
    for (int p = 0; p < 4; ++p) {
      const int c = (tid & 3) * 4 + p * 16;
      float4 f = *(const float4*)(w + ((size_t)(h * E_ + e0 + r)) * D_ + c);
      s[r][c] = f.x; s[r][c+1] = f.y; s[r][c+2] = f.z; s[r][c+3] = f.w;
    }
  }
  __syncthreads();
  {
    const int d = tid >> 2, ec = (tid & 3) * 16;
    unsigned short tmp[16];
    #pragma unroll
    for (int j = 0; j < 16; ++j) tmp[j] = f2bf(s[ec + j][d]);
    unsigned short* dst = o + ((size_t)(h * D_ + d)) * E_ + e0 + ec;
    *(bf16x8*)(dst)     = *(const bf16x8*)&tmp[0];
    *(bf16x8*)(dst + 8) = *(const bf16x8*)&tmp[8];
  }
}

// ---------------------------------------------------------------------------
// QKV projection (double-buffered global_load_lds). grid (T/128, H, B) = 512.
// q/k epilogues use swapped-operand MFMA (C col = t) for ushort4 stores;
// v written transposed [d][t]. q pre-scaled by QSCALE.
// ---------------------------------------------------------------------------
__global__ __launch_bounds__(256) void proj_kernel(
    const unsigned short* __restrict__ in16,
    const unsigned short* __restrict__ qwt, const unsigned short* __restrict__ kwt,
    const unsigned short* __restrict__ vwt,
    const float* __restrict__ qb, const float* __restrict__ kb, const float* __restrict__ vb,
    unsigned short* __restrict__ qo, unsigned short* __restrict__ ko,
    unsigned short* __restrict__ vt)
{
  __shared__ __align__(16) unsigned short in_s[2][128 * 64];   // 32 KB
  __shared__ __align__(16) unsigned short w_s[2][3][64 * 64];  // 48 KB
  const int tid = threadIdx.x;
  const int lane = tid & 63, wv = tid >> 6;
  const int l15 = lane & 15, quad = lane >> 4;
  const int t0 = blockIdx.x * 128, h = blockIdx.y, b = blockIdx.z;
  const int bh = b * H_ + h;
  const unsigned short* wts[3] = { qwt, kwt, vwt };

  f32x4 acc[3][2][4];
  #pragma unroll
  for (int x = 0; x < 3; ++x)
    #pragma unroll
    for (int s = 0; s < 2; ++s)
      #pragma unroll
      for (int nb = 0; nb < 4; ++nb) acc[x][s][nb] = (f32x4){0.f, 0.f, 0.f, 0.f};

#define PROJ_STAGE(e0_, bi_)                                                      \
  {                                                                               \
    const unsigned short* gin = in16 + ((size_t)(b * T_ + t0)) * E_ + (e0_);      \
    _Pragma("unroll")                                                             \
    for (int p = 0; p < 4; ++p) {                                                 \
      const int br = wv * 32 + p * 8;                                             \
      dma8(gin + (size_t)br * E_, E_, &in_s[bi_][br * 64], lane);                 \
    }                                                                             \
    _Pragma("unroll")                                                             \
    for (int j = 0; j < 6; ++j) {                                                 \
      const int idx = wv * 6 + j;                                                 \
      const int x = idx >> 3, br = (idx & 7) * 8;                                 \
      dma8(wts[x] + ((size_t)(h * D_ + br)) * E_ + (e0_), E_,                     \
           &w_s[bi_][x][br * 64], lane);                                          \
    }                                                                             \
  }

  PROJ_STAGE(0, 0);
  __syncthreads();
  for (int e = 0; e < 16; ++e) {
    const int bi = e & 1;
    if (e < 15) PROJ_STAGE((e + 1) * 64, bi ^ 1);
    const unsigned short* is = in_s[bi];
    #pragma unroll
    for (int kk = 0; kk < 2; ++kk) {
      const int g0 = kk * 4 + quad;
      bf16x8 a0 = frag(is, wv * 32 + l15, g0);
      bf16x8 a1 = frag(is, wv * 32 + 16 + l15, g0);
      #pragma unroll
      for (int x = 0; x < 3; ++x) {
        const unsigned short* ws = w_s[bi][x];
        #pragma unroll
        for (int nb = 0; nb < 4; ++nb) {
          bf16x8 bfr = frag(ws, nb * 16 + l15, g0);
          if (x < 2) {   // q,k: A=w (m=d), B=in (n=t) -> C col=t, rows=d
            acc[x][0][nb] = __builtin_amdgcn_mfma_f32_16x16x32_bf16(bfr, a0, acc[x][0][nb], 0, 0, 0);
            acc[x][1][nb] = __builtin_amdgcn_mfma_f32_16x16x32_bf16(bfr, a1, acc[x][1][nb], 0, 0, 0);
          } else {       // v: A=in (m=t), B=w (n=d) -> C col=d, rows=t
            acc[x][0][nb] = __builtin_amdgcn_mfma_f32_16x16x32_bf16(a0, bfr, acc[x][0][nb], 0, 0, 0);
            acc[x][1][nb] = __builtin_amdgcn_mfma_f32_16x16x32_bf16(a1, bfr, acc[x][1][nb], 0, 0, 0);
          }
        }
      }
    }
    __syncthreads();
  }
#undef PROJ_STAGE

  const size_t obase = (size_t)bh * T_;
  // q (scaled) and k: lane t fixed, 4 consecutive d -> ushort4 stores
  #pragma unroll
  for (int x = 0; x < 2; ++x) {
    const float scl = (x == 0) ? QSCALE : 1.0f;
    const float* bias = (x == 0) ? qb : kb;
    unsigned short* outp = (x == 0) ? qo : ko;
    #pragma unroll
    for (int nb = 0; nb < 4; ++nb) {
      float bias4[4];
      *(float4*)bias4 = *(const float4*)&bias[h * D_ + nb * 16 + quad * 4];
      #pragma unroll
      for (int s = 0; s < 2; ++s) {
        const int t = t0 + wv * 32 + s * 16 + l15;
        unsigned short pk[4];
        #pragma unroll
        for (int r = 0; r < 4; ++r) pk[r] = f2bf((acc[x][s][nb][r] + bias4[r]) * scl);
        *(ushort4*)(outp + (obase + t) * D_ + nb * 16 + quad * 4) = *(const ushort4*)pk;
      }
    }
  }
  // v: transposed [d][t] — lane d fixed, 4 consecutive t -> ushort4 stores
  #pragma unroll
  for (int nb = 0; nb < 4; ++nb) {
    const int d = nb * 16 + l15;
    const float bvv = vb[h * D_ + d];
    #pragma unroll
    for (int s = 0; s < 2; ++s) {
      const int t = t0 + wv * 32 + s * 16 + quad * 4;
      unsigned short pk[4];
      #pragma unroll
      for (int r = 0; r < 4; ++r) pk[r] = f2bf(acc[2][s][nb][r] + bvv);
      *(ushort4*)(vt + ((size_t)(bh * D_ + d)) * T_ + t) = *(const ushort4*)pk;
    }
  }
}

// ---------------------------------------------------------------------------
// Column softmax: lg[s] = -log2( sum_t exp2(S'[t,s]) ). grid (H, B, 16) =
// 512 blocks, 2/CU. Block owns PAIRED s-tiles (sa=p, sb=31-p): uniform 33
// MFMA-units/block; each staged Q tile feeds both. K B-frags for both tiles
// reg-resident (one-time); Q dbuf via dma8. 16.5 KB LDS.
// ---------------------------------------------------------------------------
__global__ __launch_bounds__(256) void stats_kernel(
    const unsigned short* __restrict__ q, const unsigned short* __restrict__ k,
    float* __restrict__ lg)
{
  __shared__ __align__(16) unsigned short q_s[2][64 * 64];   // 16 KB
  __shared__ float red[4][2][64];
  const int tid = threadIdx.x;
  const int lane = tid & 63, wv = tid >> 6;
  const int l15 = lane & 15, quad = lane >> 4;
  const int h = blockIdx.x, b = blockIdx.y, p = blockIdx.z;
  const int sa = p, sb = 31 - p;
  const int s0a = sa * 64, s0b = sb * 64;
  const int bh = b * H_ + h;
  const unsigned short* qbase = q + (size_t)bh * T_ * 64;

  bf16x8 kf[2][4][2];                            // reg-resident K B-frags, both tiles
  #pragma unroll
  for (int tl = 0; tl < 2; ++tl) {
    const int s0 = tl ? s0b : s0a;
    #pragma unroll
    for (int nb = 0; nb < 4; ++nb)
      #pragma unroll
      for (int kk = 0; kk < 2; ++kk)
        kf[tl][nb][kk] = *(const bf16x8*)(k + ((size_t)(bh * T_ + s0 + nb * 16 + l15)) * 64
                                            + kk * 32 + quad * 8);
  }

  #pragma unroll
  for (int pp = 0; pp < 2; ++pp) {
    const int br = wv * 16 + pp * 8;
    dma8(qbase + (size_t)(sa * 64 + br) * 64, 64, &q_s[0][br * 64], lane);
  }
  __syncthreads();

  float lsum[2][4];
  #pragma unroll
  for (int tl = 0; tl < 2; ++tl)
    #pragma unroll
    for (int nb = 0; nb < 4; ++nb) lsum[tl][nb] = 0.f;

  for (int tt = sa, i = 0; tt < NT_; ++tt, ++i) {
    const int bi = i & 1;
    if (tt + 1 < NT_) {
      #pragma unroll
      for (int pp = 0; pp < 2; ++pp) {
        const int br = wv * 16 + pp * 8;
        dma8(qbase + (size_t)((tt + 1) * 64 + br) * 64, 64, &q_s[bi ^ 1][br * 64], lane);
      }
    }
    bf16x8 a0 = frag(q_s[bi], wv * 16 + l15, quad);
    bf16x8 a1 = frag(q_s[bi], wv * 16 + l15, 4 + quad);
    {                                            // tile a (always active)
      f32x4 sacc[4];
      #pragma unroll
      for (int nb = 0; nb < 4; ++nb) sacc[nb] = (f32x4){0.f, 0.f, 0.f, 0.f};
      #pragma unroll
      for (int nb = 0; nb < 4; ++nb) {
        sacc[nb] = __builtin_amdgcn_mfma_f32_16x16x32_bf16(a0, kf[0][nb][0], sacc[nb], 0, 0, 0);
        sacc[nb] = __builtin_amdgcn_mfma_f32_16x16x32_bf16(a1, kf[0][nb][1], sacc[nb], 0, 0, 0);
      }
      if (tt == sa) {                            // diagonal: causal mask
        const int tbase = tt * 64 + wv * 16 + quad * 4;
        #pragma unroll
        for (int nb = 0; nb < 4; ++nb) {
          const int s = s0a + nb * 16 + l15;
          #pragma unroll
          for (int r = 0; r < 4; ++r)
            lsum[0][nb] += (tbase + r >= s) ? EXP2(sacc[nb][r]) : 0.f;
        }
      } else {
        #pragma unroll
        for (int nb = 0; nb < 4; ++nb)
          #pragma unroll
          for (int r = 0; r < 4; ++r) lsum[0][nb] += EXP2(sacc[nb][r]);
      }
    }
    if (tt >= sb) {                              // tile b
      f32x4 sacc[4];
      #pragma unroll
      for (int nb = 0; nb < 4; ++nb) sacc[nb] = (f32x4){0.f, 0.f, 0.f, 0.f};
      #pragma unroll
      for (int nb = 0; nb < 4; ++nb) {
        sacc[nb] = __builtin_amdgcn_mfma_f32_16x16x32_bf16(a0, kf[1][nb][0], sacc[nb], 0, 0, 0);
        sacc[nb] = __builtin_amdgcn_mfma_f32_16x16x32_bf16(a1, kf[1][nb][1], sacc[nb], 0, 0, 0);
      }
      if (tt == sb) {
        const int tbase = tt * 64 + wv * 16 + quad * 4;
        #pragma unroll
        for (int nb = 0; nb < 4; ++nb) {
          const int s = s0b + nb * 16 + l15;
          #pragma unroll
          for (int r = 0; r < 4; ++r)
            lsum[1][nb] += (tbase + r >= s) ? EXP2(sacc[nb][r]) : 0.f;
        }
      } else {
        #pragma unroll
        for (int nb = 0; nb < 4; ++nb)
          #pragma unroll
          for (int r = 0; r < 4; ++r) lsum[1][nb] += EXP2(sacc[nb][r]);
      }
    }
    __syncthreads();
  }
  #pragma unroll
  for (int tl = 0; tl < 2; ++tl)
    #pragma unroll
    for (int nb = 0; nb < 4; ++nb) {
      lsum[tl][nb] += __shfl_xor(lsum[tl][nb], 16);
      lsum[tl][nb] += __shfl_xor(lsum[tl][nb], 32);
    }
  if (lane < 16) {
    #pragma unroll
    for (int tl = 0; tl < 2; ++tl)
      #pragma unroll
      for (int nb = 0; nb < 4; ++nb) red[wv][tl][nb * 16 + lane] = lsum[tl][nb];
  }
  __syncthreads();
  if (tid < 128) {
    const int tl = tid >> 6, sL = tid & 63;
    const float L = red[0][tl][sL] + red[1][tl][sL] + red[2][tl][sL] + red[3][tl][sL];
    lg[(size_t)bh * T_ + (tl ? s0b : s0a) + sL] = -__log2f(L);
  }
}

// ---------------------------------------------------------------------------
// Output. grid (H, B, 16) = 512 blocks, 2/CU. Block owns PAIRED t-tiles
// (ja=p, jb=31-p): each staged K/Vt/lg s-unit feeds both tiles (K A-frags
// read once) — uniform 33 MFMA-units/block. K/Vt/lg double-buffered dma8
// (~42 KB LDS). S^T with sacc init = lg[s] (1/l fused into exp2); U through
// wave-private LDS; O^T = Vt.U^T -> float4 coalesced stores.
// ---------------------------------------------------------------------------
__global__ __launch_bounds__(256) void out_kernel(
    const unsigned short* __restrict__ q, const unsigned short* __restrict__ k,
    const unsigned short* __restrict__ vt, const float* __restrict__ lg,
    float* __restrict__ out)
{
  __shared__ __align__(16) unsigned short k_s[2][64 * 64];    // 16 KB
  __shared__ __align__(16) unsigned short vt_s[2][64 * 64];   // 16 KB
  __shared__ __align__(16) unsigned short u_s[4][16][72];     // 9.2 KB wave-private
  __shared__ float lg_sh[2][64];
  const int tid = threadIdx.x;
  const int lane = tid & 63, wv = tid >> 6;
  const int l15 = lane & 15, quad = lane >> 4;
  const int h = blockIdx.x, b = blockIdx.y, p = blockIdx.z;
  const int ja = p, jb = 31 - p;
  const int t0a = ja * 64, t0b = jb * 64;
  const int bh = b * H_ + h;
  const unsigned short* kbase = k + (size_t)bh * T_ * 64;
  const unsigned short* vbase = vt + (size_t)bh * D_ * T_;
  const float* lgbase = lg + (size_t)bh * T_;

  // one-time Q B-frags for both tiles (direct global)
  bf16x8 qf[2][2];
  #pragma unroll
  for (int ti = 0; ti < 2; ++ti) {
    const unsigned short* qrow =
        q + (size_t)(bh * T_ + (ti ? t0b : t0a) + wv * 16 + l15) * 64;
    qf[ti][0] = *(const bf16x8*)(qrow + quad * 8);
    qf[ti][1] = *(const bf16x8*)(qrow + 32 + quad * 8);
  }

  // stage unit 0 into slot 0
  #pragma unroll
  for (int pp = 0; pp < 2; ++pp) {
    const int br = wv * 16 + pp * 8;
    dma8(kbase + (size_t)br * 64, 64, &k_s[0][br * 64], lane);
    dma8(vbase + (size_t)br * T_, T_, &vt_s[0][br * 64], lane);
  }
  if (tid < 64) lg_sh[0][tid] = lgbase[tid];
  __syncthreads();

  f32x4 oacc[2][4];
  #pragma unroll
  for (int ti = 0; ti < 2; ++ti)
    #pragma unroll
    for (int nb = 0; nb < 4; ++nb) oacc[ti][nb] = (f32x4){0.f, 0.f, 0.f, 0.f};

  unsigned short* urow = &u_s[wv][l15][0];
  const int tcola = t0a + wv * 16 + l15;
  const int tcolb = t0b + wv * 16 + l15;

  for (int st = 0; st <= jb; ++st) {
    const int bi = st & 1;
    if (st < jb) {                               // prefetch next unit
      const int s1 = (st + 1) * 64;
      #pragma unroll
      for (int pp = 0; pp < 2; ++pp) {
        const int br = wv * 16 + pp * 8;
        dma8(kbase + (size_t)(s1 + br) * 64, 64, &k_s[bi ^ 1][br * 64], lane);
        dma8(vbase + (size_t)br * T_ + s1, T_, &vt_s[bi ^ 1][br * 64], lane);
      }
      if (tid < 64) lg_sh[bi ^ 1][tid] = lgbase[s1 + tid];
    }
    const int s0 = st * 64;
    const unsigned short* ks = k_s[bi];
    const unsigned short* vs = vt_s[bi];
    const float* lgb = lg_sh[bi];
    // K A-frags: shared by both tiles
    bf16x8 ka[4][2];
    #pragma unroll
    for (int mb = 0; mb < 4; ++mb) {
      ka[mb][0] = frag(ks, mb * 16 + l15, quad);
      ka[mb][1] = frag(ks, mb * 16 + l15, 4 + quad);
    }
    #pragma unroll
    for (int ti = 0; ti < 2; ++ti) {
      if (ti == 0 && st > ja) continue;          // tile a finished
      const int jt = ti ? jb : ja;
      const int tcol = ti ? tcolb : tcola;
      f32x4 sacc[4];
      #pragma unroll
      for (int mb = 0; mb < 4; ++mb) {
        float lg4[4];
        *(float4*)lg4 = *(const float4*)&lgb[mb * 16 + quad * 4];
        sacc[mb] = (f32x4){lg4[0], lg4[1], lg4[2], lg4[3]};
      }
      #pragma unroll
      for (int mb = 0; mb < 4; ++mb) {
        sacc[mb] = __builtin_amdgcn_mfma_f32_16x16x32_bf16(ka[mb][0], qf[ti][0], sacc[mb], 0, 0, 0);
        sacc[mb] = __builtin_amdgcn_mfma_f32_16x16x32_bf16(ka[mb][1], qf[ti][1], sacc[mb], 0, 0, 0);
      }
      // U = exp2(S' + lg[s]), masked on this tile's diagonal
      if (st == jt) {
        #pragma unroll
        for (int mb = 0; mb < 4; ++mb) {
          const int sbase = s0 + mb * 16 + quad * 4;
          float uu[4] = { EXP2(sacc[mb][0]), EXP2(sacc[mb][1]),
                          EXP2(sacc[mb][2]), EXP2(sacc[mb][3]) };
          #pragma unroll
          for (int r = 0; r < 4; ++r) if (tcol < sbase + r) uu[r] = 0.f;
          *(uint2*)(urow + mb * 16 + quad * 4) =
              make_uint2(pk2bf(uu[0], uu[1]), pk2bf(uu[2], uu[3]));
        }
      } else {
        #pragma unroll
        for (int mb = 0; mb < 4; ++mb) {
          float uu[4] = { EXP2(sacc[mb][0]), EXP2(sacc[mb][1]),
                          EXP2(sacc[mb][2]), EXP2(sacc[mb][3]) };
          *(uint2*)(urow + mb * 16 + quad * 4) =
              make_uint2(pk2bf(uu[0], uu[1]), pk2bf(uu[2], uu[3]));
        }
      }
      // O^T += Vt . U^T — same-wave LDS dependency only
      #pragma unroll
      for (int kk = 0; kk < 2; ++kk) {
        bf16x8 ua = *(const bf16x8*)(urow + kk * 32 + quad * 8);
        #pragma unroll
        for (int nb = 0; nb < 4; ++nb)
          oacc[ti][nb] = __builtin_amdgcn_mfma_f32_16x16x32_bf16(
              frag(vs, nb * 16 + l15, kk * 4 + quad), ua, oacc[ti][nb], 0, 0, 0);
      }
    }
    __syncthreads();
  }
  // O^T C-layout: lane t fixed, rows = d -> float4 coalesced stores
  #pragma unroll
  for (int ti = 0; ti < 2; ++ti) {
    const int t0 = ti ? t0b : t0a;
    float* orow = out + ((size_t)(b * T_ + t0 + wv * 16 + l15)) * (H_ * D_) + h * D_;
    #pragma unroll
    for (int nb = 0; nb < 4; ++nb) {
      float o4[4] = { oacc[ti][nb][0], oacc[ti][nb][1], oacc[ti][nb][2], oacc[ti][nb][3] };
      *(float4*)(orow + nb * 16 + quad * 4) = *(const float4*)o4;
    }
  }
}

extern "C" void kernel_launch(void* const* d_in, const int* in_sizes, int n_in,
                              void* d_out, int out_size, void* d_ws, size_t ws_size,
                              hipStream_t stream) {
  const float* in = (const float*)d_in[0];
  const float* kw = (const float*)d_in[1];
  const float* kb = (const float*)d_in[2];
  const float* qw = (const float*)d_in[3];
  const float* qb = (const float*)d_in[4];
  const float* vw = (const float*)d_in[5];
  const float* vb = (const float*)d_in[6];
  float* out = (float*)d_out;

  // ws (bf16): in16 | qwt|kwt|vwt (H,D,E) | q16|k16 (B,H,T,D) | vt (B,H,D,T) | lg fp32
  unsigned short* p = (unsigned short*)d_ws;
  const size_t inz = (size_t)B_ * T_ * E_;
  const size_t wz  = (size_t)H_ * D_ * E_;
  const size_t qz  = (size_t)B_ * H_ * T_ * D_;
  unsigned short* in16 = p;            p += inz;
  unsigned short* qwt  = p;            p += wz;
  unsigned short* kwt  = p;            p += wz;
  unsigned short* vwt  = p;            p += wz;
  unsigned short* q16  = p;            p += qz;
  unsigned short* k16  = p;            p += qz;
  unsigned short* vtb  = p;            p += qz;
  float* lgbuf = (float*)p;

  dim3 blk(256);
  inpack_kernel<<<dim3(inz / 2048), blk, 0, stream>>>(in, in16);
  wpack_kernel <<<dim3(E_ / 64, H_, 3), blk, 0, stream>>>(qw, kw, vw, qwt, kwt, vwt);
  proj_kernel  <<<dim3(T_ / 128, H_, B_), blk, 0, stream>>>(in16, qwt, kwt, vwt,
                                                            qb, kb, vb, q16, k16, vtb);
  stats_kernel <<<dim3(H_, B_, 16), blk, 0, stream>>>(q16, k16, lgbuf);
  out_kernel   <<<dim3(H_, B_, 16), blk, 0, stream>>>(q16, k16, vtb, lgbuf, out);
}

// Round 8
// 170.885 us; speedup vs baseline: 1.0792x; 1.0792x over previous
//
#include <hip/hip_runtime.h>
#include <hip/hip_bf16.h>
#include <math.h>

#define B_ 2
#define T_ 2048
#define E_ 1024
#define H_ 16
#define D_ 64
#define NT_ 32          // T/64 tiles
#define QSCALE 0.180336880f   // 0.125 * log2(e): folded into q so exp(S/8) = exp2(S')

typedef __attribute__((ext_vector_type(8))) short bf16x8;   // MFMA A/B frag (4 VGPRs)
typedef __attribute__((ext_vector_type(4))) float f32x4;    // MFMA C/D frag

#if __has_builtin(__builtin_amdgcn_exp2f)
#define EXP2(x) __builtin_amdgcn_exp2f(x)
#else
#define EXP2(x) exp2f(x)
#endif

__device__ __forceinline__ unsigned short f2bf(float x) {   // RNE fp32->bf16
  union { float f; unsigned u; } v; v.f = x;
  unsigned r = v.u + 0x7FFFu + ((v.u >> 16) & 1u);
  return (unsigned short)(r >> 16);
}
__device__ __forceinline__ unsigned pk2bf(float a, float b) {  // low=a, high=b (HW cvt_pk)
  __hip_bfloat162 h = __float22bfloat162_rn(make_float2(a, b));
  union { __hip_bfloat162 h; unsigned u; } c; c.h = h; return c.u;
}

// Async global->LDS: one wave-instr stages 8 rows x 64 bf16 (8 blocks of 16B),
// XOR-swizzled: LDS slot (row, bs) holds global block bs ^ (row&7).
__device__ __forceinline__ void dma8(const unsigned short* g, int gstride,
                                     unsigned short* l, int lane)
{
  const int r = lane >> 3, bg = (lane & 7) ^ (r & 7);
  __builtin_amdgcn_global_load_lds(
      (const __attribute__((address_space(1))) void*)(g + (size_t)r * gstride + bg * 8),
      (__attribute__((address_space(3))) void*)l, 16, 0, 0);
}
__device__ __forceinline__ bf16x8 frag(const unsigned short* tile, int row, int g) {
  return *(const bf16x8*)(tile + row * 64 + (((g ^ row) & 7) << 3));
}

// ---------------------------------------------------------------------------
// fused pack: blocks [0,2048) = input fp32->bf16; [2048,2816) = weight
// transpose (H,E,D) fp32 -> (H,D,E) bf16.
// ---------------------------------------------------------------------------
__global__ __launch_bounds__(256) void pack_kernel(
    const float* __restrict__ in, unsigned short* __restrict__ o16,
    const float* __restrict__ qw, const float* __restrict__ kw, const float* __restrict__ vw,
    unsigned short* __restrict__ qwt, unsigned short* __restrict__ kwt,
    unsigned short* __restrict__ vwt)
{
  __shared__ float s[64][65];
  const int tid = threadIdx.x;
  if (blockIdx.x < 2048) {                       // input pack
    const size_t i = ((size_t)blockIdx.x * 256 + tid) * 8;
    float4 f0 = *(const float4*)(in + i);
    float4 f1 = *(const float4*)(in + i + 4);
    unsigned u[4] = { pk2bf(f0.x, f0.y), pk2bf(f0.z, f0.w),
                      pk2bf(f1.x, f1.y), pk2bf(f1.z, f1.w) };
    *(bf16x8*)(o16 + i) = *(const bf16x8*)u;
    return;
  }
  const int i = blockIdx.x - 2048;
  const int e0 = (i & 15) * 64, h = (i >> 4) & 15, z = i >> 8;
  const float* w = (z == 0) ? qw : (z == 1) ? kw : vw;
  unsigned short* o = (z == 0) ? qwt : (z == 1) ? kwt : vwt;
  {
    const int r = tid >> 2;
    #pragma unroll
    for (int p = 0; p < 4; ++p) {
      const int c = (tid & 3) * 4 + p * 16;
      float4 f = *(const float4*)(w + ((size_t)(h * E_ + e0 + r)) * D_ + c);
      s[r][c] = f.x; s[r][c+1] = f.y; s[r][c+2] = f.z; s[r][c+3] = f.w;
    }
  }
  __syncthreads();
  {
    const int d = tid >> 2, ec = (tid & 3) * 16;
    unsigned short tmp[16];
    #pragma unroll
    for (int j = 0; j < 16; ++j) tmp[j] = f2bf(s[ec + j][d]);
    unsigned short* dst = o + ((size_t)(h * D_ + d)) * E_ + e0 + ec;
    *(bf16x8*)(dst)     = *(const bf16x8*)&tmp[0];
    *(bf16x8*)(dst + 8) = *(const bf16x8*)&tmp[8];
  }
}

// ---------------------------------------------------------------------------
// QKV projection. grid (T/128, H, B) = 512. Wave retile: wave wv owns
// n-blocks {q:wv, k:wv, v:wv} (16-wide each, compile-time x) for ALL 128 t —
// 22 LDS frag reads/wave/iter (was 28), 48 MFMA. BK=64, dbuf dma8 staging.
// ---------------------------------------------------------------------------
__global__ __launch_bounds__(256) void proj_kernel(
    const unsigned short* __restrict__ in16,
    const unsigned short* __restrict__ qwt, const unsigned short* __restrict__ kwt,
    const unsigned short* __restrict__ vwt,
    const float* __restrict__ qb, const float* __restrict__ kb, const float* __restrict__ vb,
    unsigned short* __restrict__ qo, unsigned short* __restrict__ ko,
    unsigned short* __restrict__ vt)
{
  __shared__ __align__(16) unsigned short in_s[2][128 * 64];   // 32 KB
  __shared__ __align__(16) unsigned short w_s[2][3 * 64 * 64]; // 48 KB (flat rows: x*64+d)
  const int tid = threadIdx.x;
  const int lane = tid & 63, wv = tid >> 6;
  const int l15 = lane & 15, quad = lane >> 4;
  const int t0 = blockIdx.x * 128, h = blockIdx.y, b = blockIdx.z;
  const int bh = b * H_ + h;
  const unsigned short* wts[3] = { qwt, kwt, vwt };

  f32x4 acc[3][8];
  #pragma unroll
  for (int x = 0; x < 3; ++x)
    #pragma unroll
    for (int tb = 0; tb < 8; ++tb) acc[x][tb] = (f32x4){0.f, 0.f, 0.f, 0.f};

#define PROJ_STAGE(e0_, bi_)                                                      \
  {                                                                               \
    const unsigned short* gin = in16 + ((size_t)(b * T_ + t0)) * E_ + (e0_);      \
    _Pragma("unroll")                                                             \
    for (int p = 0; p < 4; ++p) {                                                 \
      const int br = wv * 32 + p * 8;                                             \
      dma8(gin + (size_t)br * E_, E_, &in_s[bi_][br * 64], lane);                 \
    }                                                                             \
    _Pragma("unroll")                                                             \
    for (int j = 0; j < 6; ++j) {                                                 \
      const int idx = wv * 6 + j;                                                 \
      const int x = idx >> 3, br = (idx & 7) * 8;                                 \
      dma8(wts[x] + ((size_t)(h * D_ + br)) * E_ + (e0_), E_,                     \
           &w_s[bi_][x * 4096 + br * 64], lane);                                  \
    }                                                                             \
  }

  PROJ_STAGE(0, 0);
  __syncthreads();
  for (int e = 0; e < 16; ++e) {
    const int bi = e & 1;
    if (e < 15) PROJ_STAGE((e + 1) * 64, bi ^ 1);
    const unsigned short* is = in_s[bi];
    const unsigned short* ws = w_s[bi];
    #pragma unroll
    for (int kk = 0; kk < 2; ++kk) {
      const int g0 = kk * 4 + quad;
      bf16x8 bfr[3];
      #pragma unroll
      for (int x = 0; x < 3; ++x)
        bfr[x] = frag(ws, x * 64 + wv * 16 + l15, g0);
      bf16x8 afr[8];
      #pragma unroll
      for (int tb = 0; tb < 8; ++tb)
        afr[tb] = frag(is, tb * 16 + l15, g0);
      #pragma unroll
      for (int tb = 0; tb < 8; ++tb) {
        // q,k: A=w (m=d), B=in (n=t) -> C col=t; v: A=in (m=t), B=w -> C col=d
        acc[0][tb] = __builtin_amdgcn_mfma_f32_16x16x32_bf16(bfr[0], afr[tb], acc[0][tb], 0, 0, 0);
        acc[1][tb] = __builtin_amdgcn_mfma_f32_16x16x32_bf16(bfr[1], afr[tb], acc[1][tb], 0, 0, 0);
        acc[2][tb] = __builtin_amdgcn_mfma_f32_16x16x32_bf16(afr[tb], bfr[2], acc[2][tb], 0, 0, 0);
      }
    }
    __syncthreads();
  }
#undef PROJ_STAGE

  const size_t obase = (size_t)bh * T_;
  // q (scaled) and k: lane t = tb*16+l15, 4 consecutive d -> ushort4 stores
  #pragma unroll
  for (int x = 0; x < 2; ++x) {
    const float scl = (x == 0) ? QSCALE : 1.0f;
    const float* bias = (x == 0) ? qb : kb;
    unsigned short* outp = (x == 0) ? qo : ko;
    float bias4[4];
    *(float4*)bias4 = *(const float4*)&bias[h * D_ + wv * 16 + quad * 4];
    #pragma unroll
    for (int tb = 0; tb < 8; ++tb) {
      const int t = t0 + tb * 16 + l15;
      unsigned short pk[4];
      #pragma unroll
      for (int r = 0; r < 4; ++r) pk[r] = f2bf((acc[x][tb][r] + bias4[r]) * scl);
      *(ushort4*)(outp + (obase + t) * D_ + wv * 16 + quad * 4) = *(const ushort4*)pk;
    }
  }
  // v: transposed [d][t] — lane d = wv*16+l15, 4 consecutive t -> ushort4
  {
    const int d = wv * 16 + l15;
    const float bvv = vb[h * D_ + d];
    #pragma unroll
    for (int tb = 0; tb < 8; ++tb) {
      const int t = t0 + tb * 16 + quad * 4;
      unsigned short pk[4];
      #pragma unroll
      for (int r = 0; r < 4; ++r) pk[r] = f2bf(acc[2][tb][r] + bvv);
      *(ushort4*)(vt + ((size_t)(bh * D_ + d)) * T_ + t) = *(const ushort4*)pk;
    }
  }
}

// ---------------------------------------------------------------------------
// Column softmax: lg[s] = -log2( sum_t exp2(S'[t,s]) ). grid (H, B, NT) =
// 1024 blocks, 4/CU; sa=0 (heaviest) first. K B-frags reg-resident
// (one-time), Q dbuf via dma8. 16.5 KB LDS.
// ---------------------------------------------------------------------------
__global__ __launch_bounds__(256) void stats_kernel(
    const unsigned short* __restrict__ q, const unsigned short* __restrict__ k,
    float* __restrict__ lg)
{
  __shared__ __align__(16) unsigned short q_s[2][64 * 64];   // 16 KB
  __shared__ float red[4][64];
  const int tid = threadIdx.x;
  const int lane = tid & 63, wv = tid >> 6;
  const int l15 = lane & 15, quad = lane >> 4;
  const int h = blockIdx.x, b = blockIdx.y, sa = blockIdx.z;
  const int bh = b * H_ + h;
  const int s0 = sa * 64;
  const unsigned short* qbase = q + (size_t)bh * T_ * 64;

  bf16x8 kf[4][2];                               // reg-resident K B-frags (one-time)
  #pragma unroll
  for (int nb = 0; nb < 4; ++nb)
    #pragma unroll
    for (int kk = 0; kk < 2; ++kk)
      kf[nb][kk] = *(const bf16x8*)(k + ((size_t)(bh * T_ + s0 + nb * 16 + l15)) * 64
                                      + kk * 32 + quad * 8);

  #pragma unroll
  for (int pp = 0; pp < 2; ++pp) {
    const int br = wv * 16 + pp * 8;
    dma8(qbase + (size_t)(sa * 64 + br) * 64, 64, &q_s[0][br * 64], lane);
  }
  __syncthreads();

  float lsum[4] = {0.f, 0.f, 0.f, 0.f};

  for (int tt = sa, i = 0; tt < NT_; ++tt, ++i) {
    const int bi = i & 1;
    if (tt + 1 < NT_) {
      #pragma unroll
      for (int pp = 0; pp < 2; ++pp) {
        const int br = wv * 16 + pp * 8;
        dma8(qbase + (size_t)((tt + 1) * 64 + br) * 64, 64, &q_s[bi ^ 1][br * 64], lane);
      }
    }
    bf16x8 a0 = frag(q_s[bi], wv * 16 + l15, quad);
    bf16x8 a1 = frag(q_s[bi], wv * 16 + l15, 4 + quad);
    f32x4 sacc[4];
    #pragma unroll
    for (int nb = 0; nb < 4; ++nb) sacc[nb] = (f32x4){0.f, 0.f, 0.f, 0.f};
    #pragma unroll
    for (int nb = 0; nb < 4; ++nb) {
      sacc[nb] = __builtin_amdgcn_mfma_f32_16x16x32_bf16(a0, kf[nb][0], sacc[nb], 0, 0, 0);
      sacc[nb] = __builtin_amdgcn_mfma_f32_16x16x32_bf16(a1, kf[nb][1], sacc[nb], 0, 0, 0);
    }
    if (tt == sa) {                              // diagonal tile: causal mask
      const int tbase = tt * 64 + wv * 16 + quad * 4;
      #pragma unroll
      for (int nb = 0; nb < 4; ++nb) {
        const int s = s0 + nb * 16 + l15;
        #pragma unroll
        for (int r = 0; r < 4; ++r)
          lsum[nb] += (tbase + r >= s) ? EXP2(sacc[nb][r]) : 0.f;
      }
    } else {
      #pragma unroll
      for (int nb = 0; nb < 4; ++nb)
        #pragma unroll
        for (int r = 0; r < 4; ++r) lsum[nb] += EXP2(sacc[nb][r]);
    }
    __syncthreads();
  }
  #pragma unroll
  for (int nb = 0; nb < 4; ++nb) {
    lsum[nb] += __shfl_xor(lsum[nb], 16);
    lsum[nb] += __shfl_xor(lsum[nb], 32);
  }
  if (lane < 16) {
    #pragma unroll
    for (int nb = 0; nb < 4; ++nb) red[wv][nb * 16 + lane] = lsum[nb];
  }
  __syncthreads();
  if (tid < 64) {
    const float L = red[0][tid] + red[1][tid] + red[2][tid] + red[3][tid];
    lg[(size_t)bh * T_ + s0 + tid] = -__log2f(L);
  }
}

// ---------------------------------------------------------------------------
// Output. grid (H, B, NT) = 1024 blocks, jt = 31-z heavy-first. K/Vt/lg
// DOUBLE-BUFFERED dma8 (42.5 KB LDS -> 3 blocks/CU): one barrier per unit,
// drain covered by the compute phase. S^T = K.Q^T with sacc init = lg[s]
// (1/l fused into exp2); U via wave-private LDS; O^T = Vt.U^T -> float4
// coalesced stores.
// ---------------------------------------------------------------------------
__global__ __launch_bounds__(256) void out_kernel(
    const unsigned short* __restrict__ q, const unsigned short* __restrict__ k,
    const unsigned short* __restrict__ vt, const float* __restrict__ lg,
    float* __restrict__ out)
{
  __shared__ __align__(16) unsigned short k_s[2][64 * 64];    // 16 KB
  __shared__ __align__(16) unsigned short vt_s[2][64 * 64];   // 16 KB
  __shared__ __align__(16) unsigned short u_s[4][16][72];     // 9.2 KB wave-private
  __shared__ float lg_sh[2][64];
  const int tid = threadIdx.x;
  const int lane = tid & 63, wv = tid >> 6;
  const int l15 = lane & 15, quad = lane >> 4;
  const int h = blockIdx.x, b = blockIdx.y, jt = 31 - blockIdx.z;
  const int bh = b * H_ + h;
  const int t0 = jt * 64;
  const unsigned short* kbase = k + (size_t)bh * T_ * 64;
  const unsigned short* vbase = vt + (size_t)bh * D_ * T_;
  const float* lgbase = lg + (size_t)bh * T_;

  // one-time Q B-frags (direct global)
  const unsigned short* qrow = q + (size_t)(bh * T_ + t0 + wv * 16 + l15) * 64;
  bf16x8 qf0 = *(const bf16x8*)(qrow + quad * 8);
  bf16x8 qf1 = *(const bf16x8*)(qrow + 32 + quad * 8);

  // stage unit 0 into slot 0
  #pragma unroll
  for (int pp = 0; pp < 2; ++pp) {
    const int br = wv * 16 + pp * 8;
    dma8(kbase + (size_t)br * 64, 64, &k_s[0][br * 64], lane);
    dma8(vbase + (size_t)br * T_, T_, &vt_s[0][br * 64], lane);
  }
  if (tid < 64) lg_sh[0][tid] = lgbase[tid];
  __syncthreads();

  f32x4 oacc[4];
  #pragma unroll
  for (int nb = 0; nb < 4; ++nb) oacc[nb] = (f32x4){0.f, 0.f, 0.f, 0.f};

  unsigned short* urow = &u_s[wv][l15][0];
  const int tcol = t0 + wv * 16 + l15;

  for (int st = 0; st <= jt; ++st) {
    const int bi = st & 1;
    if (st < jt) {                               // prefetch next unit
      const int s1 = (st + 1) * 64;
      #pragma unroll
      for (int pp = 0; pp < 2; ++pp) {
        const int br = wv * 16 + pp * 8;
        dma8(kbase + (size_t)(s1 + br) * 64, 64, &k_s[bi ^ 1][br * 64], lane);
        dma8(vbase + (size_t)br * T_ + s1, T_, &vt_s[bi ^ 1][br * 64], lane);
      }
      if (tid < 64) lg_sh[bi ^ 1][tid] = lgbase[s1 + tid];
    }
    const int s0 = st * 64;
    const unsigned short* ks = k_s[bi];
    const unsigned short* vs = vt_s[bi];
    const float* lgb = lg_sh[bi];
    // S^T tile: A = K rows (s), B = Q (reg); C init = lg[s] fuses 1/l
    f32x4 sacc[4];
    #pragma unroll
    for (int mb = 0; mb < 4; ++mb) {
      float lg4[4];
      *(float4*)lg4 = *(const float4*)&lgb[mb * 16 + quad * 4];
      sacc[mb] = (f32x4){lg4[0], lg4[1], lg4[2], lg4[3]};
    }
    #pragma unroll
    for (int mb = 0; mb < 4; ++mb) {
      bf16x8 ka0 = frag(ks, mb * 16 + l15, quad);
      bf16x8 ka1 = frag(ks, mb * 16 + l15, 4 + quad);
      sacc[mb] = __builtin_amdgcn_mfma_f32_16x16x32_bf16(ka0, qf0, sacc[mb], 0, 0, 0);
      sacc[mb] = __builtin_amdgcn_mfma_f32_16x16x32_bf16(ka1, qf1, sacc[mb], 0, 0, 0);
    }
    // U = exp2(S' + lg[s]), masked on diagonal; write wave-private row
    if (st == jt) {
      #pragma unroll
      for (int mb = 0; mb < 4; ++mb) {
        const int sbase = s0 + mb * 16 + quad * 4;
        float uu[4] = { EXP2(sacc[mb][0]), EXP2(sacc[mb][1]),
                        EXP2(sacc[mb][2]), EXP2(sacc[mb][3]) };
        #pragma unroll
        for (int r = 0; r < 4; ++r) if (tcol < sbase + r) uu[r] = 0.f;
        *(uint2*)(urow + mb * 16 + quad * 4) =
            make_uint2(pk2bf(uu[0], uu[1]), pk2bf(uu[2], uu[3]));
      }
    } else {
      #pragma unroll
      for (int mb = 0; mb < 4; ++mb) {
        float uu[4] = { EXP2(sacc[mb][0]), EXP2(sacc[mb][1]),
                        EXP2(sacc[mb][2]), EXP2(sacc[mb][3]) };
        *(uint2*)(urow + mb * 16 + quad * 4) =
            make_uint2(pk2bf(uu[0], uu[1]), pk2bf(uu[2], uu[3]));
      }
    }
    // O^T += Vt . U^T : A = Vt rows (d), B = own U row — same-wave LDS dep
    #pragma unroll
    for (int kk = 0; kk < 2; ++kk) {
      bf16x8 ua = *(const bf16x8*)(urow + kk * 32 + quad * 8);
      #pragma unroll
      for (int nb = 0; nb < 4; ++nb)
        oacc[nb] = __builtin_amdgcn_mfma_f32_16x16x32_bf16(
            frag(vs, nb * 16 + l15, kk * 4 + quad), ua, oacc[nb], 0, 0, 0);
    }
    __syncthreads();   // waves done with slot bi; prefetch into bi^1 drained
  }
  // O^T C-layout: lane t fixed, rows = d -> float4 coalesced stores
  float* orow = out + ((size_t)(b * T_ + t0 + wv * 16 + l15)) * (H_ * D_) + h * D_;
  #pragma unroll
  for (int nb = 0; nb < 4; ++nb) {
    float o4[4] = { oacc[nb][0], oacc[nb][1], oacc[nb][2], oacc[nb][3] };
    *(float4*)(orow + nb * 16 + quad * 4) = *(const float4*)o4;
  }
}

extern "C" void kernel_launch(void* const* d_in, const int* in_sizes, int n_in,
                              void* d_out, int out_size, void* d_ws, size_t ws_size,
                              hipStream_t stream) {
  const float* in = (const float*)d_in[0];
  const float* kw = (const float*)d_in[1];
  const float* kb = (const float*)d_in[2];
  const float* qw = (const float*)d_in[3];
  const float* qb = (const float*)d_in[4];
  const float* vw = (const float*)d_in[5];
  const float* vb = (const float*)d_in[6];
  float* out = (float*)d_out;

  // ws (bf16): in16 | qwt|kwt|vwt (H,D,E) | q16|k16 (B,H,T,D) | vt (B,H,D,T) | lg fp32
  unsigned short* p = (unsigned short*)d_ws;
  const size_t inz = (size_t)B_ * T_ * E_;
  const size_t wz  = (size_t)H_ * D_ * E_;
  const size_t qz  = (size_t)B_ * H_ * T_ * D_;
  unsigned short* in16 = p;            p += inz;
  unsigned short* qwt  = p;            p += wz;
  unsigned short* kwt  = p;            p += wz;
  unsigned short* vwt  = p;            p += wz;
  unsigned short* q16  = p;            p += qz;
  unsigned short* k16  = p;            p += qz;
  unsigned short* vtb  = p;            p += qz;
  float* lgbuf = (float*)p;

  dim3 blk(256);
  pack_kernel <<<dim3(2048 + 768), blk, 0, stream>>>(in, in16, qw, kw, vw, qwt, kwt, vwt);
  proj_kernel <<<dim3(T_ / 128, H_, B_), blk, 0, stream>>>(in16, qwt, kwt, vwt,
                                                           qb, kb, vb, q16, k16, vtb);
  stats_kernel<<<dim3(H_, B_, NT_), blk, 0, stream>>>(q16, k16, lgbuf);
  out_kernel  <<<dim3(H_, B_, NT_), blk, 0, stream>>>(q16, k16, vtb, lgbuf, out);
}